// Round 1
// baseline (22512.912 us; speedup 1.0000x reference)
//
#include <hip/hip_runtime.h>
#include <math.h>

// GPT-2 small forward: B=2, T=1024, C=768, H=12, D=64, L=12, FF=3072, V=50257
#define TT 1024
#define CC 768
#define HH 12
#define DD 64
#define FF_DIM 3072
#define VV 50257
#define LL 12
#define BT_ROWS 2048   // B*T

// ---------------- embedding ----------------
__global__ __launch_bounds__(256) void embed_kernel(
    const int* __restrict__ idx, const float* __restrict__ tok,
    const float* __restrict__ pos, float* __restrict__ x) {
  int row = blockIdx.x;                 // 0..2047
  int t = row & (TT - 1);
  int token = idx[row];
  const float* tp = tok + (size_t)token * CC;
  const float* pp = pos + (size_t)t * CC;
  float* xp = x + (size_t)row * CC;
  for (int c = threadIdx.x; c < CC; c += 256)
    xp[c] = tp[c] + pp[c];
}

// ---------------- layernorm ----------------
__global__ __launch_bounds__(256) void ln_kernel(
    const float* __restrict__ x, const float* __restrict__ s,
    const float* __restrict__ b, float* __restrict__ out) {
  int row = blockIdx.x;
  const float* xr = x + (size_t)row * CC;
  float vals[3];
  float sum = 0.f, sq = 0.f;
#pragma unroll
  for (int i = 0; i < 3; ++i) {
    float v = xr[threadIdx.x + 256 * i];
    vals[i] = v;
    sum += v;
    sq += v * v;
  }
#pragma unroll
  for (int off = 32; off; off >>= 1) {
    sum += __shfl_xor(sum, off);
    sq += __shfl_xor(sq, off);
  }
  __shared__ float red[8];
  int lane = threadIdx.x & 63, wid = threadIdx.x >> 6;
  if (lane == 0) { red[wid] = sum; red[4 + wid] = sq; }
  __syncthreads();
  sum = red[0] + red[1] + red[2] + red[3];
  sq = red[4] + red[5] + red[6] + red[7];
  float mean = sum * (1.0f / CC);
  float var = sq * (1.0f / CC) - mean * mean;
  float rstd = rsqrtf(var + 1e-5f);
  float* op = out + (size_t)row * CC;
#pragma unroll
  for (int i = 0; i < 3; ++i) {
    int c = threadIdx.x + 256 * i;
    op[c] = (vals[i] - mean) * rstd * s[c] + b[c];
  }
}

// ---------------- tiled fp32 GEMM ----------------
// out[M,N] = act(A[M,K] @ W[K,N] + bias) (+ resid).  BM=BN=64, BK=16, 256 thr, 4x4/thr.
#define BM 64
#define BN 64
#define BK 16

template <bool GELU, bool ALIGNED_N>
__global__ __launch_bounds__(256) void gemm_kernel(
    const float* __restrict__ A, const float* __restrict__ W,
    const float* __restrict__ bias, const float* __restrict__ resid,
    float* __restrict__ out, int M, int N, int K) {
  __shared__ float As[BK][BM + 4];
  __shared__ float Bs[BK][BN + 4];
  int tid = threadIdx.x;
  int tr = tid >> 4;             // 0..15
  int tc = tid & 15;             // 0..15
  int m0 = blockIdx.y * BM;
  int n0 = blockIdx.x * BN;
  int aRow = tid >> 2;           // 0..63
  int aCol = (tid & 3) << 2;     // 0,4,8,12
  int bRow = tid >> 4;           // 0..15
  int bCol = (tid & 15) << 2;    // 0..60
  float acc[4][4] = {};

  for (int k0 = 0; k0 < K; k0 += BK) {
    // A tile (M,K divisible by 64/16; always aligned)
    float4 av = *(const float4*)(A + (size_t)(m0 + aRow) * K + k0 + aCol);
    As[aCol + 0][aRow] = av.x;
    As[aCol + 1][aRow] = av.y;
    As[aCol + 2][aRow] = av.z;
    As[aCol + 3][aRow] = av.w;
    // B tile
    const float* wp = W + (size_t)(k0 + bRow) * N;
    int gn = n0 + bCol;
    if (ALIGNED_N) {
      float4 bv = *(const float4*)(wp + gn);
      *(float4*)&Bs[bRow][bCol] = bv;
    } else {
      Bs[bRow][bCol + 0] = (gn + 0 < N) ? wp[gn + 0] : 0.f;
      Bs[bRow][bCol + 1] = (gn + 1 < N) ? wp[gn + 1] : 0.f;
      Bs[bRow][bCol + 2] = (gn + 2 < N) ? wp[gn + 2] : 0.f;
      Bs[bRow][bCol + 3] = (gn + 3 < N) ? wp[gn + 3] : 0.f;
    }
    __syncthreads();
#pragma unroll
    for (int k = 0; k < BK; ++k) {
      float4 a = *(const float4*)&As[k][tr << 2];
      float4 b = *(const float4*)&Bs[k][tc << 2];
      acc[0][0] += a.x * b.x; acc[0][1] += a.x * b.y; acc[0][2] += a.x * b.z; acc[0][3] += a.x * b.w;
      acc[1][0] += a.y * b.x; acc[1][1] += a.y * b.y; acc[1][2] += a.y * b.z; acc[1][3] += a.y * b.w;
      acc[2][0] += a.z * b.x; acc[2][1] += a.z * b.y; acc[2][2] += a.z * b.z; acc[2][3] += a.z * b.w;
      acc[3][0] += a.w * b.x; acc[3][1] += a.w * b.y; acc[3][2] += a.w * b.z; acc[3][3] += a.w * b.w;
    }
    __syncthreads();
  }

#pragma unroll
  for (int i = 0; i < 4; ++i) {
    int m = m0 + (tr << 2) + i;
    float* op = out + (size_t)m * N;
    const float* rp = resid ? (resid + (size_t)m * N) : nullptr;
#pragma unroll
    for (int j = 0; j < 4; ++j) {
      int n = n0 + (tc << 2) + j;
      if (ALIGNED_N || n < N) {
        float v = acc[i][j];
        if (bias) v += bias[n];
        if (GELU) v = 0.5f * v * (1.0f + erff(v * 0.70710678118654752f));
        if (rp) v += rp[n];
        op[n] = v;
      }
    }
  }
}

// ---------------- attention: one wave per (b,h,qrow), online softmax ----------------
__global__ __launch_bounds__(256) void attn_kernel(
    const float* __restrict__ qkv, float* __restrict__ y) {
  int lane = threadIdx.x & 63;
  int wid = blockIdx.x * 4 + (threadIdx.x >> 6);  // 0 .. B*H*T-1
  int qr = wid & (TT - 1);
  int bh = wid >> 10;       // b*H + h
  int h = bh % HH;
  int b = bh / HH;
  const float* base = qkv + (size_t)(b * TT) * (3 * CC);
  float q = base[(size_t)qr * (3 * CC) + h * DD + lane] * 0.125f;

  float m = -INFINITY, l = 0.f, acc = 0.f;
  for (int j = 0; j <= qr; ++j) {
    const float* kp = base + (size_t)j * (3 * CC) + CC + h * DD;
    float kd = kp[lane];
    float vd = kp[CC + lane];
    float s = q * kd;
#pragma unroll
    for (int off = 32; off; off >>= 1) s += __shfl_xor(s, off);
    float mn = fmaxf(m, s);
    float sc = __expf(m - mn);
    float p = __expf(s - mn);
    l = l * sc + p;
    acc = acc * sc + p * vd;
    m = mn;
  }
  y[((size_t)(b * TT) + qr) * CC + h * DD + lane] = acc / l;
}

// ---------------- launch ----------------
extern "C" void kernel_launch(void* const* d_in, const int* in_sizes, int n_in,
                              void* d_out, int out_size, void* d_ws, size_t ws_size,
                              hipStream_t stream) {
  const int* idx = (const int*)d_in[0];
  const float* tok_emb = (const float*)d_in[1];
  const float* pos_emb = (const float*)d_in[2];
  const float* ln1_s = (const float*)d_in[3];
  const float* ln1_b = (const float*)d_in[4];
  const float* Wqkv = (const float*)d_in[5];
  const float* bqkv = (const float*)d_in[6];
  const float* Wo = (const float*)d_in[7];
  const float* bo = (const float*)d_in[8];
  const float* ln2_s = (const float*)d_in[9];
  const float* ln2_b = (const float*)d_in[10];
  const float* Wfc = (const float*)d_in[11];
  const float* bfc = (const float*)d_in[12];
  const float* Wpr = (const float*)d_in[13];
  const float* bpr = (const float*)d_in[14];
  const float* lnf_s = (const float*)d_in[15];
  const float* lnf_b = (const float*)d_in[16];
  const float* Whead = (const float*)d_in[17];
  float* logits = (float*)d_out;

  float* ws = (float*)d_ws;
  float* x = ws;                         // 2048*768
  float* h = x + (size_t)BT_ROWS * CC;   // 2048*768
  float* qkv = h + (size_t)BT_ROWS * CC; // 2048*2304
  float* y = qkv + (size_t)BT_ROWS * 3 * CC;   // 2048*768
  float* ffn = y + (size_t)BT_ROWS * CC;       // 2048*3072

  dim3 blk(256);
  embed_kernel<<<BT_ROWS, blk, 0, stream>>>(idx, tok_emb, pos_emb, x);

  for (int l = 0; l < LL; ++l) {
    const float* wqkv = Wqkv + (size_t)l * CC * 3 * CC;
    const float* bq = bqkv + (size_t)l * 3 * CC;
    const float* wo = Wo + (size_t)l * CC * CC;
    const float* bo_ = bo + (size_t)l * CC;
    const float* wfc = Wfc + (size_t)l * CC * FF_DIM;
    const float* bf = bfc + (size_t)l * FF_DIM;
    const float* wpr = Wpr + (size_t)l * FF_DIM * CC;
    const float* bp = bpr + (size_t)l * CC;

    ln_kernel<<<BT_ROWS, blk, 0, stream>>>(x, ln1_s + l * CC, ln1_b + l * CC, h);
    gemm_kernel<false, true><<<dim3(3 * CC / BN, BT_ROWS / BM), blk, 0, stream>>>(
        h, wqkv, bq, nullptr, qkv, BT_ROWS, 3 * CC, CC);
    attn_kernel<<<(2 * HH * TT) / 4, blk, 0, stream>>>(qkv, y);
    gemm_kernel<false, true><<<dim3(CC / BN, BT_ROWS / BM), blk, 0, stream>>>(
        y, wo, bo_, x, x, BT_ROWS, CC, CC);
    ln_kernel<<<BT_ROWS, blk, 0, stream>>>(x, ln2_s + l * CC, ln2_b + l * CC, h);
    gemm_kernel<true, true><<<dim3(FF_DIM / BN, BT_ROWS / BM), blk, 0, stream>>>(
        h, wfc, bf, nullptr, ffn, BT_ROWS, FF_DIM, CC);
    gemm_kernel<false, true><<<dim3(CC / BN, BT_ROWS / BM), blk, 0, stream>>>(
        ffn, wpr, bp, x, x, BT_ROWS, CC, FF_DIM);
  }

  ln_kernel<<<BT_ROWS, blk, 0, stream>>>(x, lnf_s, lnf_b, h);
  gemm_kernel<false, false><<<dim3((VV + BN - 1) / BN, BT_ROWS / BM), blk, 0, stream>>>(
      h, Whead, nullptr, nullptr, logits, BT_ROWS, VV, CC);
}